// Round 8
// baseline (425.708 us; speedup 1.0000x reference)
//
#include <hip/hip_runtime.h>
#include <stdint.h>

typedef unsigned long long u64;
typedef unsigned int u32;

// ---------------------------------------------------------------------------
// Constants: 17 feats/row, beta = col 9, cc = cols 14..16, T_B=0.85, T_D^2=0.09.
// Greedy condensation == scan candidates in descending (betaBits, ~idx) key
// order, accept iff not within T_D of any previously accepted center.
// R8: incremental masked dense scan (each candidate x center pair checked at
// most ONCE over the kernel; no compaction/ballot/ffsll/insertion-ladder/
// bisection -- each of those was a measured regression in R3..R7) + the
// 1-barrier-per-pick exact pop (top-2-with-coords per thread, kill-on-commit,
// horizon H = block-max 3rd-best key).
// ---------------------------------------------------------------------------

__global__ void init_kernel(int* segCount, int* condCount, int nseg) {
    int t = threadIdx.x;
    if (t < nseg) { segCount[t] = 0; condCount[t] = 0; }
}

// Single-pass filter: block-local LDS staging, ONE global atomic per block.
__launch_bounds__(256)
__global__ void filter_kernel(const float* __restrict__ x, int S, int chunk, int bps,
                              int* __restrict__ segCount,
                              float4* __restrict__ A, int* __restrict__ iA, int CAP) {
    __shared__ float4 stg[1024];
    __shared__ int sgi[1024];
    __shared__ int s_cnt, s_base;
    int b = blockIdx.x;
    int s = b / bps, c = b % bps;
    int start = s * S + c * chunk;
    int end = min(start + chunk, s * S + S);
    if (threadIdx.x == 0) s_cnt = 0;
    __syncthreads();
    for (int i = start + threadIdx.x; i < end; i += 256) {
        float beta = x[(size_t)i * 17 + 9];
        if (beta >= 0.85f) {
            int p = atomicAdd(&s_cnt, 1);
            if (p < 1024) {
                stg[p] = make_float4(x[(size_t)i * 17 + 14], x[(size_t)i * 17 + 15],
                                     x[(size_t)i * 17 + 16], beta);
                sgi[p] = i;
            }
        }
    }
    __syncthreads();
    if (threadIdx.x == 0) s_base = atomicAdd(&segCount[s], min(s_cnt, 1024));
    __syncthreads();
    int cnt = min(s_cnt, 1024);
    for (int k = threadIdx.x; k < cnt; k += 256) {
        int pos = s_base + k;
        if (pos < CAP) {
            A[(size_t)s * CAP + pos] = stg[k];
            iA[(size_t)s * CAP + pos] = sgi[k];
        }
    }
}

#define DSQ(ax,ay,az,bx,by,bz) \
    __fadd_rn(__fadd_rn(__fmul_rn(__fsub_rn(ax,bx),__fsub_rn(ax,bx)), \
                        __fmul_rn(__fsub_rn(ay,by),__fsub_rn(ay,by))), \
              __fmul_rn(__fsub_rn(az,bz),__fsub_rn(az,bz)))

// One block (1024 thr) per segment.
__launch_bounds__(1024)
__global__ void greedy_kernel(const float4* __restrict__ A, const int* __restrict__ iA,
                              const int* __restrict__ candCount, int CAP,
                              int* __restrict__ condList, int* __restrict__ condCount,
                              int CCAP) {
    const int s = blockIdx.x;
    const int tid = threadIdx.x;
    const int lane = tid & 63;
    const int wid = tid >> 6;

    __shared__ float4 ctr[1024];
    __shared__ int ctrGi[1024];
    __shared__ u64 wkey[2][16];
    __shared__ float4 wctr[2][16];
    __shared__ u64 s_H;
    __shared__ int s_alive;

    const float4* cand = A + (size_t)s * CAP;
    const int* gia = iA + (size_t)s * CAP;
    int n = candCount[s]; if (n > CAP) n = CAP;

    // alive bit t <-> candidate j = tid + (t<<10)
    int nslots = (n > tid) ? ((n - tid + 1023) >> 10) : 0;
    u64 alive = (nslots >= 64) ? ~0ull : ((1ull << nslots) - 1ull);

    int condTotal = 0, scanned = 0, passes = 0, par = 0;

    while (true) {
        if (tid == 0) { s_H = 0; s_alive = 0; }
        __syncthreads();

        // ---- SCAN: dense masked loop; coverage vs NEW centers only;
        //      top-2 (with coords) + 3rd-best key ----
        u64 k1 = 0, k2 = 0, k3 = 0;
        float x1=0,y1=0,z1=0, x2=0,y2=0,z2=0;
        int myAlive = 0;
        for (int t = 0; t < 64; ++t) {
            int j = tid + (t << 10);
            if (j >= n) break;
            if (!((alive >> t) & 1ull)) continue;
            float4 c = cand[j];
            bool live = true;
            for (int m = scanned; m < condTotal; ++m) {
                float4 q = ctr[m];   // uniform m -> LDS broadcast
                if (DSQ(c.x, c.y, c.z, q.x, q.y, q.z) < 0.09f) { live = false; break; }
            }
            if (!live) { alive &= ~(1ull << t); continue; }
            ++myAlive;
            u64 key = ((u64)__float_as_uint(c.w) << 32) | (u64)(~(u32)gia[j]);
            if (key > k1) {
                k3 = k2;
                k2 = k1; x2 = x1; y2 = y1; z2 = z1;
                k1 = key; x1 = c.x; y1 = c.y; z1 = c.z;
            } else if (key > k2) {
                k3 = k2;
                k2 = key; x2 = c.x; y2 = c.y; z2 = c.z;
            } else if (key > k3) {
                k3 = key;
            }
        }

        // ---- reduce alive count and horizon H = block-max k3 ----
        int asum = myAlive; u64 h = k3;
        for (int off = 32; off > 0; off >>= 1) {
            asum += __shfl_down(asum, off);
            u64 o = __shfl_down(h, off);
            if (o > h) h = o;
        }
        if (lane == 0) { atomicAdd(&s_alive, asum); atomicMax(&s_H, h); }
        __syncthreads();
        if (s_alive == 0) break;        // everything covered: done
        u64 H = s_H;
        scanned = condTotal;            // next pass checks centers from here

        // ---- POP: one barrier per committed pick; every iter commits ----
        while (condTotal < 1024) {
            u64 mk; float bx, by, bz;
            if (k1 >= k2) { mk = k1; bx = x1; by = y1; bz = z1; }
            else          { mk = k2; bx = x2; by = y2; bz = z2; }
            for (int off = 32; off > 0; off >>= 1) {
                u64 ok = __shfl_xor(mk, off);
                float ox = __shfl_xor(bx, off);
                float oy = __shfl_xor(by, off);
                float oz = __shfl_xor(bz, off);
                if (ok > mk) { mk = ok; bx = ox; by = oy; bz = oz; }
            }
            if (lane == 0) { wkey[par][wid] = mk; wctr[par][wid] = make_float4(bx, by, bz, 0.f); }
            __syncthreads();
            u64 bk = 0; int bL = 0;
            #pragma unroll
            for (int w = 0; w < 16; ++w) {
                u64 kk = wkey[par][w];
                if (kk > bk) { bk = kk; bL = w; }
            }
            if (bk <= H) break;                 // hidden candidates all <= H
            float4 cc = wctr[par][bL];          // uniform -> LDS broadcast
            // kill own pending entries covered by the new center
            if (k1 && DSQ(x1, y1, z1, cc.x, cc.y, cc.z) < 0.09f) k1 = 0;
            if (k2 && DSQ(x2, y2, z2, cc.x, cc.y, cc.z) < 0.09f) k2 = 0;
            if (tid == 0) {
                ctr[condTotal] = cc;
                ctrGi[condTotal] = (int)(~(u32)(bk & 0xFFFFFFFFull));
            }
            condTotal++;                        // uniform
            par ^= 1;
        }
        __syncthreads();   // pop LDS quiesced before next-pass reset
        if (condTotal >= 1024 || ++passes > 128) break;   // safety
    }

    for (int i = tid; i < condTotal; i += 1024)
        condList[(size_t)s * CCAP + i] = ctrGi[i];
    if (tid == 0) condCount[s] = condTotal;
}

// Rank-sort each segment's pick list ascending, global sorted order,
// ncond cumulative counts as float32.
__global__ void finalize_kernel(const int* __restrict__ condList,
                                const int* __restrict__ condCount, int CCAP,
                                int* __restrict__ sorted, int* __restrict__ prefix,
                                float* __restrict__ ncond_out, int nseg, int rows) {
    __shared__ int lst[2048];
    __shared__ int pfx[9];
    int tid = threadIdx.x;
    if (tid == 0) {
        int acc = 0; pfx[0] = 0;
        for (int s2 = 0; s2 < nseg; s2++) { acc += condCount[s2]; pfx[s2 + 1] = acc; }
    }
    __syncthreads();
    if (tid <= nseg) { prefix[tid] = pfx[tid]; ncond_out[tid] = (float)pfx[tid]; }
    for (int s2 = 0; s2 < nseg; s2++) {
        int ns = condCount[s2]; if (ns > CCAP) ns = CCAP;
        for (int i = tid; i < ns; i += blockDim.x) lst[i] = condList[(size_t)s2 * CCAP + i];
        __syncthreads();
        for (int i = tid; i < ns; i += blockDim.x) {
            int v = lst[i]; int rank = 0;
            for (int j = 0; j < ns; j++) rank += (lst[j] < v);
            int pos = pfx[s2] + rank;
            if (pos < rows) sorted[pos] = v;
        }
        __syncthreads();
    }
}

__global__ void emit_kernel(const float* __restrict__ x, const int* __restrict__ sorted,
                            const int* __restrict__ prefix, float* __restrict__ out,
                            int rows, int nseg) {
    int e = blockIdx.x * blockDim.x + threadIdx.x;
    if (e >= rows * 17) return;
    int total = prefix[nseg];
    int j = e / 17, k = e - j * 17;
    float v = 0.f;
    if (j < total) v = x[(size_t)sorted[j] * 17 + k];
    out[e] = v;
}

extern "C" void kernel_launch(void* const* d_in, const int* in_sizes, int n_in,
                              void* d_out, int out_size, void* d_ws, size_t ws_size,
                              hipStream_t stream) {
    const float* x = (const float*)d_in[0];
    const int nseg = in_sizes[1] - 1;          // 4
    const int N = in_sizes[0] / 17;            // 1,000,000
    const int S = N / nseg;                    // 250,000
    const int rows = (out_size - (nseg + 1)) / 17;  // 1024 (MAX_COND)
    const int CCAP = 2048;

    const int bps = 1024 / nseg;               // blocks per segment (256)
    const int nBlocks = nseg * bps;            // 1024
    const int chunk = (S + bps - 1) / bps;     // 977 (< 1024 LDS staging cap)

    // workspace: [A float4][iA][condList][segCount][condCount][sorted][prefix]
    char* w = (char*)d_ws;
    size_t fixedBytes = (size_t)nseg * CCAP * 4 + (size_t)nseg * 4 * 2 +
                        (size_t)rows * 4 + (size_t)(nseg + 1) * 4 + 4096;
    size_t perCand = (size_t)nseg * (16 + 4);
    size_t avail = (ws_size > fixedBytes) ? (ws_size - fixedBytes) : 0;
    int CAP = (int)(avail / perCand);
    if (CAP > 65536) CAP = 65536;   // 64-bit alive-mask limit (64*1024)
    if (CAP < 1) CAP = 1;

    float4* A = (float4*)w;
    int* iA = (int*)(A + (size_t)nseg * CAP);
    int* condList  = iA + (size_t)nseg * CAP;
    int* segCount  = condList + (size_t)nseg * CCAP;
    int* condCount = segCount + nseg;
    int* sorted    = condCount + nseg;
    int* prefix    = sorted + rows;
    float* out = (float*)d_out;

    init_kernel<<<1, 64, 0, stream>>>(segCount, condCount, nseg);
    filter_kernel<<<nBlocks, 256, 0, stream>>>(x, S, chunk, bps, segCount, A, iA, CAP);
    greedy_kernel<<<nseg, 1024, 0, stream>>>(A, iA, segCount, CAP,
                                             condList, condCount, CCAP);
    finalize_kernel<<<1, 256, 0, stream>>>(condList, condCount, CCAP, sorted, prefix,
                                           out + (size_t)rows * 17, nseg, rows);
    emit_kernel<<<(rows * 17 + 255) / 256, 256, 0, stream>>>(x, sorted, prefix, out,
                                                             rows, nseg);
}